// Round 2
// baseline (207.185 us; speedup 1.0000x reference)
//
#include <hip/hip_runtime.h>

typedef float f32x4 __attribute__((ext_vector_type(4)));
typedef short s16x8 __attribute__((ext_vector_type(8)));

#define NB 8
#define NN 2048
#define FIN 512
#define FOUT 256
#define L2E 1.4426950408889634f

#if __has_builtin(__builtin_amdgcn_exp2f)
#define EXP2(x) __builtin_amdgcn_exp2f(x)
#else
#define EXP2(x) __expf((x)*0.6931471805599453f)
#endif

__device__ __forceinline__ unsigned short f2bf(float f) {
  unsigned u = __builtin_bit_cast(unsigned, f);
  u += 0x7fffu + ((u >> 16) & 1u);
  return (unsigned short)(u >> 16);
}

__device__ __forceinline__ unsigned pkbf(float lo, float hi) {
  unsigned r;
  asm("v_cvt_pk_bf16_f32 %0, %1, %2" : "=v"(r) : "v"(lo), "v"(hi));
  return r;
}

// ---------------- kernel 1: v1 = W @ (ht @ a1), v2 = W @ (ht @ a2) ----------------
__global__ void prep_vecs_k(const float* __restrict__ W, const float* __restrict__ HT,
                            const float* __restrict__ A, float* __restrict__ v1,
                            float* __restrict__ v2) {
  __shared__ float w1[256], w2[256];
  int t = threadIdx.x;  // 256 threads
  float s1 = 0.f, s2 = 0.f;
  for (int k = 0; k < 64; k++) {
    float h = HT[t * 64 + k];
    s1 += h * A[k];
    s2 += h * A[64 + k];
  }
  w1[t] = s1;
  w2[t] = s2;
  __syncthreads();
  for (int c = t; c < FIN; c += 256) {
    float a1 = 0.f, a2 = 0.f;
    for (int f = 0; f < FOUT; f++) {
      float w = W[c * FOUT + f];
      a1 += w * w1[f];
      a2 += w * w2[f];
    }
    v1[c] = a1;
    v2[c] = a2;
  }
}

// ---------------- kernel 2: wT[f][c] = bf16(W[c][f]) ----------------
__global__ void prep_wT_k(const float* __restrict__ W, unsigned short* __restrict__ wT) {
  int id = blockIdx.x * 256 + threadIdx.x;  // 131072 total
  int f = id >> 9, c = id & 511;
  wT[id] = f2bf(W[c * FOUT + f]);
}

// ---------------- kernel 3: hT = (X @ W)^T bf16 via MFMA; wave 0 also emits f1,f2 ----
__global__ __launch_bounds__(512) void gemm1_k(const float* __restrict__ inp,
                                               const unsigned short* __restrict__ wT,
                                               unsigned short* __restrict__ hT,
                                               const float* __restrict__ v1,
                                               const float* __restrict__ v2,
                                               float* __restrict__ f1,
                                               float* __restrict__ f2) {
  int tid = threadIdx.x;
  int w = tid >> 6, l = tid & 63, lr = l & 15, lg = l >> 4;
  int jtile = blockIdx.x * 64;  // global row base (0..16384)
  f32x4 acc[2][4] = {};
  float s1[4] = {0.f, 0.f, 0.f, 0.f}, s2[4] = {0.f, 0.f, 0.f, 0.f};
  for (int c0 = 0; c0 < FIN; c0 += 32) {
    s16x8 af[2];
#pragma unroll
    for (int mf = 0; mf < 2; mf++) {
      int f = w * 32 + mf * 16 + lr;
      af[mf] = *(const s16x8*)(wT + (size_t)f * FIN + c0 + lg * 8);
    }
    float4 va0, va1, vb0, vb1;
    if (w == 0) {
      va0 = *(const float4*)(v1 + c0 + lg * 8);
      va1 = *(const float4*)(v1 + c0 + lg * 8 + 4);
      vb0 = *(const float4*)(v2 + c0 + lg * 8);
      vb1 = *(const float4*)(v2 + c0 + lg * 8 + 4);
    }
    s16x8 bfv[4];
#pragma unroll
    for (int nf = 0; nf < 4; nf++) {
      int jg = jtile + nf * 16 + lr;
      const float* p = inp + (size_t)jg * FIN + c0 + lg * 8;
      float4 x0 = *(const float4*)p;
      float4 x1 = *(const float4*)(p + 4);
      s16x8 t;
      t[0] = (short)f2bf(x0.x); t[1] = (short)f2bf(x0.y);
      t[2] = (short)f2bf(x0.z); t[3] = (short)f2bf(x0.w);
      t[4] = (short)f2bf(x1.x); t[5] = (short)f2bf(x1.y);
      t[6] = (short)f2bf(x1.z); t[7] = (short)f2bf(x1.w);
      bfv[nf] = t;
      if (w == 0) {
        s1[nf] += x0.x * va0.x + x0.y * va0.y + x0.z * va0.z + x0.w * va0.w +
                  x1.x * va1.x + x1.y * va1.y + x1.z * va1.z + x1.w * va1.w;
        s2[nf] += x0.x * vb0.x + x0.y * vb0.y + x0.z * vb0.z + x0.w * vb0.w +
                  x1.x * vb1.x + x1.y * vb1.y + x1.z * vb1.z + x1.w * vb1.w;
      }
    }
#pragma unroll
    for (int mf = 0; mf < 2; mf++)
#pragma unroll
      for (int nf = 0; nf < 4; nf++)
        acc[mf][nf] =
            __builtin_amdgcn_mfma_f32_16x16x32_bf16(af[mf], bfv[nf], acc[mf][nf], 0, 0, 0);
  }
  int bb = jtile >> 11, jl = jtile & 2047;
#pragma unroll
  for (int mf = 0; mf < 2; mf++)
#pragma unroll
    for (int nf = 0; nf < 4; nf++)
#pragma unroll
      for (int r = 0; r < 4; r++) {
        int f = w * 32 + mf * 16 + lg * 4 + r;
        int j = jl + nf * 16 + lr;
        hT[((size_t)bb * FOUT + f) * (size_t)NN + j] = f2bf(acc[mf][nf][r]);
      }
  if (w == 0) {
#pragma unroll
    for (int nf = 0; nf < 4; nf++) {
      float a = s1[nf], b = s2[nf];
      a += __shfl_xor(a, 16); a += __shfl_xor(a, 32);
      b += __shfl_xor(b, 16); b += __shfl_xor(b, 32);
      if (lg == 0) {
        int jg = jtile + nf * 16 + lr;
        f1[jg] = a * L2E;   // pre-scaled by log2(e) for exp2 in pv
        f2[jg] = b * L2E;
      }
    }
  }
}

// ---------------- kernel 4: barrier-free fused masked-softmax + PV + ELU -----------
// Wave = 32 i-rows x 64 f-cols. Lane (lr,lg) computes p for rows i0+lr, i0+16+lr at
// cols jb+lg*8..+7 — exactly the MFMA A-frag slots. No LDS, no __syncthreads.
__global__ __launch_bounds__(256, 2) void pv_k(const int* __restrict__ adj,
                                               const unsigned short* __restrict__ hT,
                                               const float* __restrict__ f1,
                                               const float* __restrict__ f2,
                                               float* __restrict__ out) {
  int tid = threadIdx.x;
  int w = tid >> 6;  // f-slice 0..3
  int l = tid & 63, lr = l & 15, lg = l >> 4;
  int blk = blockIdx.x;      // 512
  int b = blk >> 6;          // 64 blocks per batch
  int i0 = (blk & 63) * 32;
  int f0 = w * 64;
  int ja = lg * 8;

  const int* arow0 = adj + ((size_t)(b * NN + i0 + lr)) * NN + ja;
  const int* arow1 = arow0 + (size_t)16 * NN;
  const unsigned short* hTb = hT + (size_t)b * FOUT * NN;
  const float* f2b = f2 + b * NN + ja;
  float fi0 = f1[b * NN + i0 + lr];
  float fi1 = f1[b * NN + i0 + 16 + lr];

  f32x4 acc[2][4] = {};
  float ls0 = 0.f, ls1 = 0.f;

  // p-compute for one 16-row group: 8 cols from int4 pair + float4 pair
  auto pcomp = [&](float fi, const int4& mA, const int4& mB, const float4& fA,
                   const float4& fB, float& ls) -> s16x8 {
    float e0 = fi + fA.x, e1 = fi + fA.y, e2 = fi + fA.z, e3 = fi + fA.w;
    float e4 = fi + fB.x, e5 = fi + fB.y, e6 = fi + fB.z, e7 = fi + fB.w;
    e0 = fmaxf(e0, 0.2f * e0); e1 = fmaxf(e1, 0.2f * e1);
    e2 = fmaxf(e2, 0.2f * e2); e3 = fmaxf(e3, 0.2f * e3);
    e4 = fmaxf(e4, 0.2f * e4); e5 = fmaxf(e5, 0.2f * e5);
    e6 = fmaxf(e6, 0.2f * e6); e7 = fmaxf(e7, 0.2f * e7);
    float p0 = (mA.x > 0) ? EXP2(e0) : 0.f;
    float p1 = (mA.y > 0) ? EXP2(e1) : 0.f;
    float p2 = (mA.z > 0) ? EXP2(e2) : 0.f;
    float p3 = (mA.w > 0) ? EXP2(e3) : 0.f;
    float p4 = (mB.x > 0) ? EXP2(e4) : 0.f;
    float p5 = (mB.y > 0) ? EXP2(e5) : 0.f;
    float p6 = (mB.z > 0) ? EXP2(e6) : 0.f;
    float p7 = (mB.w > 0) ? EXP2(e7) : 0.f;
    ls += ((p0 + p1) + (p2 + p3)) + ((p4 + p5) + (p6 + p7));
    union { unsigned u[4]; s16x8 v; } pk;
    pk.u[0] = pkbf(p0, p1); pk.u[1] = pkbf(p2, p3);
    pk.u[2] = pkbf(p4, p5); pk.u[3] = pkbf(p6, p7);
    return pk.v;
  };

  // one j-substep: consume regs for jb, prefetch jb+64 into the same buffer
  auto body = [&](int jb, int4& r0A, int4& r0B, int4& r1A, int4& r1B, float4& pfA,
                  float4& pfB) {
    // B-frags first (L2-hot); MFMA's waitcnt then leaves the prefetch in flight
    const unsigned short* hp = hTb + (size_t)(f0 + lr) * NN + jb + ja;
    s16x8 b0 = *(const s16x8*)(hp);
    s16x8 b1 = *(const s16x8*)(hp + 16 * NN);
    s16x8 b2 = *(const s16x8*)(hp + 32 * NN);
    s16x8 b3 = *(const s16x8*)(hp + 48 * NN);
    int4 c0A = r0A, c0B = r0B, c1A = r1A, c1B = r1B;
    float4 fA = pfA, fB = pfB;
    if (jb + 64 < NN) {
      r0A = *(const int4*)(arow0 + jb + 64);
      r0B = *(const int4*)(arow0 + jb + 68);
      r1A = *(const int4*)(arow1 + jb + 64);
      r1B = *(const int4*)(arow1 + jb + 68);
      pfA = *(const float4*)(f2b + jb + 64);
      pfB = *(const float4*)(f2b + jb + 68);
    }
    s16x8 af0 = pcomp(fi0, c0A, c0B, fA, fB, ls0);
    s16x8 af1 = pcomp(fi1, c1A, c1B, fA, fB, ls1);
    acc[0][0] = __builtin_amdgcn_mfma_f32_16x16x32_bf16(af0, b0, acc[0][0], 0, 0, 0);
    acc[0][1] = __builtin_amdgcn_mfma_f32_16x16x32_bf16(af0, b1, acc[0][1], 0, 0, 0);
    acc[0][2] = __builtin_amdgcn_mfma_f32_16x16x32_bf16(af0, b2, acc[0][2], 0, 0, 0);
    acc[0][3] = __builtin_amdgcn_mfma_f32_16x16x32_bf16(af0, b3, acc[0][3], 0, 0, 0);
    acc[1][0] = __builtin_amdgcn_mfma_f32_16x16x32_bf16(af1, b0, acc[1][0], 0, 0, 0);
    acc[1][1] = __builtin_amdgcn_mfma_f32_16x16x32_bf16(af1, b1, acc[1][1], 0, 0, 0);
    acc[1][2] = __builtin_amdgcn_mfma_f32_16x16x32_bf16(af1, b2, acc[1][2], 0, 0, 0);
    acc[1][3] = __builtin_amdgcn_mfma_f32_16x16x32_bf16(af1, b3, acc[1][3], 0, 0, 0);
  };

  // preload substeps 0 and 1 (depth-2 pipeline, two named register sets)
  int4 s0_0A = *(const int4*)(arow0 + 0), s0_0B = *(const int4*)(arow0 + 4);
  int4 s0_1A = *(const int4*)(arow1 + 0), s0_1B = *(const int4*)(arow1 + 4);
  float4 s0_fA = *(const float4*)(f2b + 0), s0_fB = *(const float4*)(f2b + 4);
  int4 s1_0A = *(const int4*)(arow0 + 32), s1_0B = *(const int4*)(arow0 + 36);
  int4 s1_1A = *(const int4*)(arow1 + 32), s1_1B = *(const int4*)(arow1 + 36);
  float4 s1_fA = *(const float4*)(f2b + 32), s1_fB = *(const float4*)(f2b + 36);

  for (int jb = 0; jb < NN; jb += 64) {
    body(jb, s0_0A, s0_0B, s0_1A, s0_1B, s0_fA, s0_fB);
    body(jb + 32, s1_0A, s1_0B, s1_1A, s1_1B, s1_fA, s1_fB);
  }

  // row-sum reduce across the 4 lg groups (replicated to all lanes)
  ls0 += __shfl_xor(ls0, 16); ls0 += __shfl_xor(ls0, 32);
  ls1 += __shfl_xor(ls1, 16); ls1 += __shfl_xor(ls1, 32);
  float rd0[4], rd1[4];
#pragma unroll
  for (int r = 0; r < 4; r++) {
    rd0[r] = 1.0f / __shfl(ls0, lg * 4 + r);
    rd1[r] = 1.0f / __shfl(ls1, lg * 4 + r);
  }

#pragma unroll
  for (int nf = 0; nf < 4; nf++)
#pragma unroll
    for (int r = 0; r < 4; r++) {
      int m0 = lg * 4 + r;
      int fcol = f0 + nf * 16 + lr;
      float v0 = acc[0][nf][r] * rd0[r];
      v0 = (v0 > 0.f) ? v0 : expm1f(v0);
      out[((size_t)(b * NN + i0 + m0)) * FOUT + fcol] = v0;
      float v1_ = acc[1][nf][r] * rd1[r];
      v1_ = (v1_ > 0.f) ? v1_ : expm1f(v1_);
      out[((size_t)(b * NN + i0 + 16 + m0)) * FOUT + fcol] = v1_;
    }
}

extern "C" void kernel_launch(void* const* d_in, const int* in_sizes, int n_in,
                              void* d_out, int out_size, void* d_ws, size_t ws_size,
                              hipStream_t stream) {
  const float* inp = (const float*)d_in[0];   // [8][2048][512] f32
  const int* adj   = (const int*)d_in[1];     // [8][2048][2048] i32
  const float* W   = (const float*)d_in[2];   // [512][256] f32
  const float* HT  = (const float*)d_in[3];   // [256][64] f32
  const float* A   = (const float*)d_in[4];   // [128][1] f32
  float* out = (float*)d_out;                 // [8][2048][256] f32

  char* ws = (char*)d_ws;
  float* v1 = (float*)ws;                            // 512 f32
  float* v2 = v1 + 512;                              // 512 f32
  float* f1 = (float*)(ws + 4096);                   // 16384 f32 (x log2e)
  float* f2 = (float*)(ws + 69632);                  // 16384 f32 (x log2e)
  unsigned short* wT = (unsigned short*)(ws + 135168);   // 256x512 bf16
  unsigned short* hT = (unsigned short*)(ws + 397312);   // 8x256x2048 bf16

  hipLaunchKernelGGL(prep_vecs_k, dim3(1), dim3(256), 0, stream, W, HT, A, v1, v2);
  hipLaunchKernelGGL(prep_wT_k, dim3(512), dim3(256), 0, stream, W, wT);
  hipLaunchKernelGGL(gemm1_k, dim3(256), dim3(512), 0, stream, inp, wT, hT, v1, v2, f1, f2);
  hipLaunchKernelGGL(pv_k, dim3(512), dim3(256), 0, stream, adj, hT, f1, f2, out);
}

// Round 5
// 193.616 us; speedup vs baseline: 1.0701x; 1.0701x over previous
//
#include <hip/hip_runtime.h>

typedef float f32x4 __attribute__((ext_vector_type(4)));
typedef short s16x8 __attribute__((ext_vector_type(8)));

#define NN 2048
#define FIN 512
#define FOUT 256
#define L2E 1.4426950408889634f

#if __has_builtin(__builtin_amdgcn_exp2f)
#define EXP2(x) __builtin_amdgcn_exp2f(x)
#else
#define EXP2(x) __expf((x)*0.6931471805599453f)
#endif

__device__ __forceinline__ unsigned short f2bf(float f) {
  unsigned u = __builtin_bit_cast(unsigned, f);
  u += 0x7fffu + ((u >> 16) & 1u);
  return (unsigned short)(u >> 16);
}

__device__ __forceinline__ unsigned pkbf(float lo, float hi) {
  unsigned r;
  asm("v_cvt_pk_bf16_f32 %0, %1, %2" : "=v"(r) : "v"(lo), "v"(hi));
  return r;
}

// ---------------- kernel 1: v1 = W @ (ht @ a1), v2 = W @ (ht @ a2) ----------------
__global__ void prep_vecs_k(const float* __restrict__ W, const float* __restrict__ HT,
                            const float* __restrict__ A, float* __restrict__ v1,
                            float* __restrict__ v2) {
  __shared__ float w1[256], w2[256];
  int t = threadIdx.x;  // 256 threads
  float s1 = 0.f, s2 = 0.f;
  for (int k = 0; k < 64; k++) {
    float h = HT[t * 64 + k];
    s1 += h * A[k];
    s2 += h * A[64 + k];
  }
  w1[t] = s1;
  w2[t] = s2;
  __syncthreads();
  for (int c = t; c < FIN; c += 256) {
    float a1 = 0.f, a2 = 0.f;
    for (int f = 0; f < FOUT; f++) {
      float w = W[c * FOUT + f];
      a1 += w * w1[f];
      a2 += w * w2[f];
    }
    v1[c] = a1;
    v2[c] = a2;
  }
}

// ---------------- kernel 2: wT[f][c] = bf16(W[c][f]) ----------------
__global__ void prep_wT_k(const float* __restrict__ W, unsigned short* __restrict__ wT) {
  int id = blockIdx.x * 256 + threadIdx.x;  // 131072 total
  int f = id >> 9, c = id & 511;
  wT[id] = f2bf(W[c * FOUT + f]);
}

// ---------------- kernel 2b: adj bit-compress (Path A only) ----------------
// Thread ct packs ints [ct*64, ct*64+64) into 2 words; bit m of flat word g is
// (adj[g*32+m] > 0).
__global__ __launch_bounds__(512) void compress_k(const int* __restrict__ adj,
                                                  unsigned* __restrict__ bits) {
  int ct = blockIdx.x * 512 + threadIdx.x;  // 0..524287
  const int4* src = (const int4*)adj + (size_t)ct * 16;
  unsigned w0 = 0u, w1 = 0u;
#pragma unroll
  for (int k = 0; k < 8; k++) {
    int4 a = src[k];
    unsigned nib = (unsigned)(a.x > 0) | ((unsigned)(a.y > 0) << 1) |
                   ((unsigned)(a.z > 0) << 2) | ((unsigned)(a.w > 0) << 3);
    w0 |= nib << (k * 4);
  }
#pragma unroll
  for (int k = 0; k < 8; k++) {
    int4 a = src[8 + k];
    unsigned nib = (unsigned)(a.x > 0) | ((unsigned)(a.y > 0) << 1) |
                   ((unsigned)(a.z > 0) << 2) | ((unsigned)(a.w > 0) << 3);
    w1 |= nib << (k * 4);
  }
  uint2 o;
  o.x = w0;
  o.y = w1;
  *(uint2*)(bits + (size_t)ct * 2) = o;
}

// ---------------- kernel 3: hT = (X @ W)^T bf16 via MFMA; wave 0 also emits f1,f2 ----
__global__ __launch_bounds__(512) void gemm1_k(const float* __restrict__ inp,
                                               const unsigned short* __restrict__ wT,
                                               unsigned short* __restrict__ hT,
                                               const float* __restrict__ v1,
                                               const float* __restrict__ v2,
                                               float* __restrict__ f1,
                                               float* __restrict__ f2) {
  int tid = threadIdx.x;
  int w = tid >> 6, l = tid & 63, lr = l & 15, lg = l >> 4;
  int jtile = blockIdx.x * 64;  // global row base (0..16384)
  f32x4 acc[2][4] = {};
  float s1[4] = {0.f, 0.f, 0.f, 0.f}, s2[4] = {0.f, 0.f, 0.f, 0.f};
  for (int c0 = 0; c0 < FIN; c0 += 32) {
    s16x8 af[2];
#pragma unroll
    for (int mf = 0; mf < 2; mf++) {
      int f = w * 32 + mf * 16 + lr;
      af[mf] = *(const s16x8*)(wT + (size_t)f * FIN + c0 + lg * 8);
    }
    float4 va0, va1, vb0, vb1;
    if (w == 0) {
      va0 = *(const float4*)(v1 + c0 + lg * 8);
      va1 = *(const float4*)(v1 + c0 + lg * 8 + 4);
      vb0 = *(const float4*)(v2 + c0 + lg * 8);
      vb1 = *(const float4*)(v2 + c0 + lg * 8 + 4);
    }
    s16x8 bfv[4];
#pragma unroll
    for (int nf = 0; nf < 4; nf++) {
      int jg = jtile + nf * 16 + lr;
      const float* p = inp + (size_t)jg * FIN + c0 + lg * 8;
      float4 x0 = *(const float4*)p;
      float4 x1 = *(const float4*)(p + 4);
      s16x8 t;
      t[0] = (short)f2bf(x0.x); t[1] = (short)f2bf(x0.y);
      t[2] = (short)f2bf(x0.z); t[3] = (short)f2bf(x0.w);
      t[4] = (short)f2bf(x1.x); t[5] = (short)f2bf(x1.y);
      t[6] = (short)f2bf(x1.z); t[7] = (short)f2bf(x1.w);
      bfv[nf] = t;
      if (w == 0) {
        s1[nf] += x0.x * va0.x + x0.y * va0.y + x0.z * va0.z + x0.w * va0.w +
                  x1.x * va1.x + x1.y * va1.y + x1.z * va1.z + x1.w * va1.w;
        s2[nf] += x0.x * vb0.x + x0.y * vb0.y + x0.z * vb0.z + x0.w * vb0.w +
                  x1.x * vb1.x + x1.y * vb1.y + x1.z * vb1.z + x1.w * vb1.w;
      }
    }
#pragma unroll
    for (int mf = 0; mf < 2; mf++)
#pragma unroll
      for (int nf = 0; nf < 4; nf++)
        acc[mf][nf] =
            __builtin_amdgcn_mfma_f32_16x16x32_bf16(af[mf], bfv[nf], acc[mf][nf], 0, 0, 0);
  }
  int bb = jtile >> 11, jl = jtile & 2047;
#pragma unroll
  for (int mf = 0; mf < 2; mf++)
#pragma unroll
    for (int nf = 0; nf < 4; nf++)
#pragma unroll
      for (int r = 0; r < 4; r++) {
        int f = w * 32 + mf * 16 + lg * 4 + r;
        int j = jl + nf * 16 + lr;
        hT[((size_t)bb * FOUT + f) * (size_t)NN + j] = f2bf(acc[mf][nf][r]);
      }
  if (w == 0) {
#pragma unroll
    for (int nf = 0; nf < 4; nf++) {
      float a = s1[nf], b = s2[nf];
      a += __shfl_xor(a, 16); a += __shfl_xor(a, 32);
      b += __shfl_xor(b, 16); b += __shfl_xor(b, 32);
      if (lg == 0) {
        int jg = jtile + nf * 16 + lr;
        f1[jg] = a * L2E;
        f2[jg] = b * L2E;
      }
    }
  }
}

// ---------------- kernel 4: barrier-free fused masked-softmax + PV + ELU -----------
// EXACT round-2-passing frame (32 i-rows x 64 f per wave, grid 512, no LDS, no
// barriers). USE_BITS only changes the mask source.
template <bool USE_BITS>
__global__ __launch_bounds__(256, 2) void pv_k(const unsigned* __restrict__ bits,
                                               const int* __restrict__ adj,
                                               const unsigned short* __restrict__ hT,
                                               const float* __restrict__ f1,
                                               const float* __restrict__ f2,
                                               float* __restrict__ out) {
  int tid = threadIdx.x;
  int w = tid >> 6;  // f-slice 0..3
  int l = tid & 63, lr = l & 15, lg = l >> 4;
  int blk = blockIdx.x;      // 512
  int b = blk >> 6;          // 64 blocks per batch
  int i0 = (blk & 63) * 32;
  int f0 = w * 64;
  int ja = lg * 8;

  const int* arow0 = adj + ((size_t)(b * NN + i0 + lr)) * NN + ja;
  const int* arow1 = arow0 + (size_t)16 * NN;
  const unsigned short* hTb = hT + (size_t)b * FOUT * NN;
  const float* f2b = f2 + b * NN + ja;
  float fi0 = f1[b * NN + i0 + lr];
  float fi1 = f1[b * NN + i0 + 16 + lr];

  f32x4 acc[2][4] = {};
  float ls0 = 0.f, ls1 = 0.f;

  // p-compute from explicit int4 masks (Path B, verbatim round 2)
  auto pcomp = [&](float fi, const int4& mA, const int4& mB, const float4& fA,
                   const float4& fB, float& ls) -> s16x8 {
    float e0 = fi + fA.x, e1 = fi + fA.y, e2 = fi + fA.z, e3 = fi + fA.w;
    float e4 = fi + fB.x, e5 = fi + fB.y, e6 = fi + fB.z, e7 = fi + fB.w;
    e0 = fmaxf(e0, 0.2f * e0); e1 = fmaxf(e1, 0.2f * e1);
    e2 = fmaxf(e2, 0.2f * e2); e3 = fmaxf(e3, 0.2f * e3);
    e4 = fmaxf(e4, 0.2f * e4); e5 = fmaxf(e5, 0.2f * e5);
    e6 = fmaxf(e6, 0.2f * e6); e7 = fmaxf(e7, 0.2f * e7);
    float p0 = (mA.x > 0) ? EXP2(e0) : 0.f;
    float p1 = (mA.y > 0) ? EXP2(e1) : 0.f;
    float p2 = (mA.z > 0) ? EXP2(e2) : 0.f;
    float p3 = (mA.w > 0) ? EXP2(e3) : 0.f;
    float p4 = (mB.x > 0) ? EXP2(e4) : 0.f;
    float p5 = (mB.y > 0) ? EXP2(e5) : 0.f;
    float p6 = (mB.z > 0) ? EXP2(e6) : 0.f;
    float p7 = (mB.w > 0) ? EXP2(e7) : 0.f;
    ls += ((p0 + p1) + (p2 + p3)) + ((p4 + p5) + (p6 + p7));
    union { unsigned u[4]; s16x8 v; } pk;
    pk.u[0] = pkbf(p0, p1); pk.u[1] = pkbf(p2, p3);
    pk.u[2] = pkbf(p4, p5); pk.u[3] = pkbf(p6, p7);
    return pk.v;
  };

  // p-compute from a byte mask (Path A)
  auto pcompb = [&](float fi, unsigned byt, const float4& fA, const float4& fB,
                    float& ls) -> s16x8 {
    float e0 = fi + fA.x, e1 = fi + fA.y, e2 = fi + fA.z, e3 = fi + fA.w;
    float e4 = fi + fB.x, e5 = fi + fB.y, e6 = fi + fB.z, e7 = fi + fB.w;
    e0 = fmaxf(e0, 0.2f * e0); e1 = fmaxf(e1, 0.2f * e1);
    e2 = fmaxf(e2, 0.2f * e2); e3 = fmaxf(e3, 0.2f * e3);
    e4 = fmaxf(e4, 0.2f * e4); e5 = fmaxf(e5, 0.2f * e5);
    e6 = fmaxf(e6, 0.2f * e6); e7 = fmaxf(e7, 0.2f * e7);
    float p0 = (byt & 1u)   ? EXP2(e0) : 0.f;
    float p1 = (byt & 2u)   ? EXP2(e1) : 0.f;
    float p2 = (byt & 4u)   ? EXP2(e2) : 0.f;
    float p3 = (byt & 8u)   ? EXP2(e3) : 0.f;
    float p4 = (byt & 16u)  ? EXP2(e4) : 0.f;
    float p5 = (byt & 32u)  ? EXP2(e5) : 0.f;
    float p6 = (byt & 64u)  ? EXP2(e6) : 0.f;
    float p7 = (byt & 128u) ? EXP2(e7) : 0.f;
    ls += ((p0 + p1) + (p2 + p3)) + ((p4 + p5) + (p6 + p7));
    union { unsigned u[4]; s16x8 v; } pk;
    pk.u[0] = pkbf(p0, p1); pk.u[1] = pkbf(p2, p3);
    pk.u[2] = pkbf(p4, p5); pk.u[3] = pkbf(p6, p7);
    return pk.v;
  };

  auto mfma8 = [&](const s16x8& af0, const s16x8& af1, int jb) {
    const unsigned short* hp = hTb + (size_t)(f0 + lr) * NN + jb + ja;
    s16x8 b0 = *(const s16x8*)(hp);
    s16x8 b1 = *(const s16x8*)(hp + 16 * NN);
    s16x8 b2 = *(const s16x8*)(hp + 32 * NN);
    s16x8 b3 = *(const s16x8*)(hp + 48 * NN);
    acc[0][0] = __builtin_amdgcn_mfma_f32_16x16x32_bf16(af0, b0, acc[0][0], 0, 0, 0);
    acc[0][1] = __builtin_amdgcn_mfma_f32_16x16x32_bf16(af0, b1, acc[0][1], 0, 0, 0);
    acc[0][2] = __builtin_amdgcn_mfma_f32_16x16x32_bf16(af0, b2, acc[0][2], 0, 0, 0);
    acc[0][3] = __builtin_amdgcn_mfma_f32_16x16x32_bf16(af0, b3, acc[0][3], 0, 0, 0);
    acc[1][0] = __builtin_amdgcn_mfma_f32_16x16x32_bf16(af1, b0, acc[1][0], 0, 0, 0);
    acc[1][1] = __builtin_amdgcn_mfma_f32_16x16x32_bf16(af1, b1, acc[1][1], 0, 0, 0);
    acc[1][2] = __builtin_amdgcn_mfma_f32_16x16x32_bf16(af1, b2, acc[1][2], 0, 0, 0);
    acc[1][3] = __builtin_amdgcn_mfma_f32_16x16x32_bf16(af1, b3, acc[1][3], 0, 0, 0);
  };

  if constexpr (USE_BITS) {
    // masks from compressed bits (L2/L3-resident); depth-1 uint2 word prefetch
    const unsigned* brow0 = bits + ((size_t)(b * NN + i0 + lr)) * 64;
    const unsigned* brow1 = brow0 + 16 * 64;
    unsigned sh = (unsigned)(lg * 8);
    uint2 cq0 = *(const uint2*)(brow0);
    uint2 cq1 = *(const uint2*)(brow1);
    float4 cfA = *(const float4*)(f2b);
    float4 cfB = *(const float4*)(f2b + 4);
    float4 cfC = *(const float4*)(f2b + 32);
    float4 cfD = *(const float4*)(f2b + 36);
    for (int jb = 0; jb < NN; jb += 64) {
      uint2 q0 = cq0, q1 = cq1;
      float4 fA = cfA, fB = cfB, fC = cfC, fD = cfD;
      if (jb + 64 < NN) {
        cq0 = *(const uint2*)(brow0 + (jb >> 5) + 2);
        cq1 = *(const uint2*)(brow1 + (jb >> 5) + 2);
        cfA = *(const float4*)(f2b + jb + 64);
        cfB = *(const float4*)(f2b + jb + 68);
        cfC = *(const float4*)(f2b + jb + 96);
        cfD = *(const float4*)(f2b + jb + 100);
      }
      {
        s16x8 af0 = pcompb(fi0, (q0.x >> sh) & 0xffu, fA, fB, ls0);
        s16x8 af1 = pcompb(fi1, (q1.x >> sh) & 0xffu, fA, fB, ls1);
        mfma8(af0, af1, jb);
      }
      {
        s16x8 af0 = pcompb(fi0, (q0.y >> sh) & 0xffu, fC, fD, ls0);
        s16x8 af1 = pcompb(fi1, (q1.y >> sh) & 0xffu, fC, fD, ls1);
        mfma8(af0, af1, jb + 32);
      }
    }
  } else {
    // verbatim round-2-passing loop: direct adj, depth-2 int4 prefetch
    int4 s0_0A = *(const int4*)(arow0 + 0), s0_0B = *(const int4*)(arow0 + 4);
    int4 s0_1A = *(const int4*)(arow1 + 0), s0_1B = *(const int4*)(arow1 + 4);
    float4 s0_fA = *(const float4*)(f2b + 0), s0_fB = *(const float4*)(f2b + 4);
    int4 s1_0A = *(const int4*)(arow0 + 32), s1_0B = *(const int4*)(arow0 + 36);
    int4 s1_1A = *(const int4*)(arow1 + 32), s1_1B = *(const int4*)(arow1 + 36);
    float4 s1_fA = *(const float4*)(f2b + 32), s1_fB = *(const float4*)(f2b + 36);

    auto body = [&](int jb, int4& r0A, int4& r0B, int4& r1A, int4& r1B, float4& pfA,
                    float4& pfB) {
      int4 c0A = r0A, c0B = r0B, c1A = r1A, c1B = r1B;
      float4 fA = pfA, fB = pfB;
      if (jb + 64 < NN) {
        r0A = *(const int4*)(arow0 + jb + 64);
        r0B = *(const int4*)(arow0 + jb + 68);
        r1A = *(const int4*)(arow1 + jb + 64);
        r1B = *(const int4*)(arow1 + jb + 68);
        pfA = *(const float4*)(f2b + jb + 64);
        pfB = *(const float4*)(f2b + jb + 68);
      }
      s16x8 af0 = pcomp(fi0, c0A, c0B, fA, fB, ls0);
      s16x8 af1 = pcomp(fi1, c1A, c1B, fA, fB, ls1);
      mfma8(af0, af1, jb);
    };

    for (int jb = 0; jb < NN; jb += 64) {
      body(jb, s0_0A, s0_0B, s0_1A, s0_1B, s0_fA, s0_fB);
      body(jb + 32, s1_0A, s1_0B, s1_1A, s1_1B, s1_fA, s1_fB);
    }
  }

  // row-sum reduce across the 4 lg groups (replicated to all lanes)
  ls0 += __shfl_xor(ls0, 16); ls0 += __shfl_xor(ls0, 32);
  ls1 += __shfl_xor(ls1, 16); ls1 += __shfl_xor(ls1, 32);
  float rd0[4], rd1[4];
#pragma unroll
  for (int r = 0; r < 4; r++) {
    rd0[r] = 1.0f / __shfl(ls0, lg * 4 + r);
    rd1[r] = 1.0f / __shfl(ls1, lg * 4 + r);
  }

#pragma unroll
  for (int nf = 0; nf < 4; nf++)
#pragma unroll
    for (int r = 0; r < 4; r++) {
      int m0 = lg * 4 + r;
      int fcol = f0 + nf * 16 + lr;
      float v0 = acc[0][nf][r] * rd0[r];
      v0 = (v0 > 0.f) ? v0 : expm1f(v0);
      out[((size_t)(b * NN + i0 + m0)) * FOUT + fcol] = v0;
      float v1_ = acc[1][nf][r] * rd1[r];
      v1_ = (v1_ > 0.f) ? v1_ : expm1f(v1_);
      out[((size_t)(b * NN + i0 + 16 + m0)) * FOUT + fcol] = v1_;
    }
}

extern "C" void kernel_launch(void* const* d_in, const int* in_sizes, int n_in,
                              void* d_out, int out_size, void* d_ws, size_t ws_size,
                              hipStream_t stream) {
  const float* inp = (const float*)d_in[0];   // [8][2048][512] f32
  const int* adj   = (const int*)d_in[1];     // [8][2048][2048] i32
  const float* W   = (const float*)d_in[2];   // [512][256] f32
  const float* HT  = (const float*)d_in[3];   // [256][64] f32
  const float* A   = (const float*)d_in[4];   // [128][1] f32
  float* out = (float*)d_out;                 // [8][2048][256] f32

  char* ws = (char*)d_ws;
  float* v1 = (float*)ws;                              // 512 f32
  float* v2 = v1 + 512;                                // 512 f32
  float* f1 = (float*)(ws + 4096);                     // 16384 f32 (x log2e)
  float* f2 = (float*)(ws + 69632);                    // 16384 f32 (x log2e)
  unsigned short* wT = (unsigned short*)(ws + 135168); // 256x512 bf16
  unsigned short* hT = (unsigned short*)(ws + 397312); // 8x256x2048 bf16 -> end 8785920
  unsigned* bits = (unsigned*)(ws + 8785920);          // 8x2048x64 u32  -> end 12980224

  const bool use_bits = (ws_size >= 12980224);

  hipLaunchKernelGGL(prep_vecs_k, dim3(1), dim3(256), 0, stream, W, HT, A, v1, v2);
  hipLaunchKernelGGL(prep_wT_k, dim3(512), dim3(256), 0, stream, W, wT);
  hipLaunchKernelGGL(gemm1_k, dim3(256), dim3(512), 0, stream, inp, wT, hT, v1, v2, f1, f2);
  if (use_bits) {
    hipLaunchKernelGGL(compress_k, dim3(1024), dim3(512), 0, stream, adj, bits);
    hipLaunchKernelGGL((pv_k<true>), dim3(512), dim3(256), 0, stream, bits, adj, hT, f1,
                       f2, out);
  } else {
    hipLaunchKernelGGL((pv_k<false>), dim3(512), dim3(256), 0, stream, bits, adj, hT, f1,
                       f2, out);
  }
}